// Round 23
// baseline (218.758 us; speedup 1.0000x reference)
//
#include <hip/hip_runtime.h>

#define HID 64
#define CH 256       // edge chunks (= k_cfill grid)
#define MAXNB 800    // LDS bucket-counter capacity (>= runtime nb = 782)
#define MAXCE 6400   // LDS chunk-sort capacity (>= runtime ce = 6250)
#define CAP 4096     // LDS bucket-stage capacity (>= max bucket size ~2300)

typedef short short8 __attribute__((ext_vector_type(8)));
typedef float f32x4 __attribute__((ext_vector_type(4)));

// ---------------- CSR build: chunk-local counting sort ----------------

__global__ __launch_bounds__(256) void k_cfill(
        const int* __restrict__ src, const int* __restrict__ dst,
        int* __restrict__ counts, int* __restrict__ loff,
        int* __restrict__ tmp, int E, int ce, int nb) {
    __shared__ int lcnt[MAXNB];
    __shared__ int lscan[MAXNB];
    __shared__ int sums[256];
    __shared__ int sorted[MAXCE];
    const int c = blockIdx.x;
    const int t = threadIdx.x;
    for (int j = t; j < nb; j += 256) lcnt[j] = 0;
    __syncthreads();
    const int s0 = c * ce, e0 = min(s0 + ce, E);
    for (int i = s0 + t; i < e0; i += 256) atomicAdd(&lcnt[dst[i] >> 7], 1);
    __syncthreads();
    for (int j = t; j < nb; j += 256) counts[(size_t)c * nb + j] = lcnt[j];
    const int per = (nb + 255) >> 8;
    const int base = t * per;
    int vals[8];
    int s = 0;
    for (int k = 0; k < per; k++) {
        int f = base + k;
        int v = (f < nb) ? lcnt[f] : 0;
        vals[k] = s;
        s += v;
    }
    sums[t] = s;
    __syncthreads();
    for (int ofs = 1; ofs < 256; ofs <<= 1) {
        int v = (t >= ofs) ? sums[t - ofs] : 0;
        __syncthreads();
        sums[t] += v;
        __syncthreads();
    }
    const int carry = (t > 0) ? sums[t - 1] : 0;
    for (int k = 0; k < per; k++) {
        int f = base + k;
        if (f < nb) {
            int ex = carry + vals[k];
            lscan[f] = ex;
            loff[(size_t)c * nb + f] = ex;
        }
    }
    __syncthreads();
    for (int i = s0 + t; i < e0; i += 256) {
        int d = dst[i];
        int sv = src[i];
        int p = atomicAdd(&lscan[d >> 7], 1);
        sorted[p] = sv | ((d & 127) << 17);
    }
    __syncthreads();
    const int n = e0 - s0;
    for (int j = t; j < n; j += 256) tmp[s0 + j] = sorted[j];
}

// bucket_base = exclusive scan of column sums of counts
__global__ __launch_bounds__(1024) void k_bbase(
        const int* __restrict__ counts, int* __restrict__ bucket_base,
        int* __restrict__ row_start, int N, int E, int nb) {
    __shared__ int sums[1024];
    const int t = threadIdx.x;
    int csum = 0;
    if (t < nb) {
#pragma unroll 8
        for (int c = 0; c < CH; c++) csum += counts[(size_t)c * nb + t];
    }
    sums[t] = csum;
    __syncthreads();
    for (int ofs = 1; ofs < 1024; ofs <<= 1) {
        int u = (t >= ofs) ? sums[t - ofs] : 0;
        __syncthreads();
        sums[t] += u;
        __syncthreads();
    }
    if (t < nb) bucket_base[t] = sums[t] - csum;
    if (t == 0) { bucket_base[nb] = E; row_start[N] = E; }
}

__global__ __launch_bounds__(256) void k_pass2(
        const int* __restrict__ tmp, const int* __restrict__ counts,
        const int* __restrict__ loff, const int* __restrict__ bucket_base,
        int* __restrict__ col, int* __restrict__ row_start,
        float* __restrict__ dis, int N, int ce, int nb) {
    __shared__ int stage[CAP];
    __shared__ int soff[256];
    __shared__ int lcnt[128];
    __shared__ int lofs[128];
    const int b = blockIdx.x;
    const int t = threadIdx.x;
    const int cnt = counts[(size_t)t * nb + b];
    const int lo  = loff[(size_t)t * nb + b];
    soff[t] = cnt;
    __syncthreads();
    for (int ofs = 1; ofs < 256; ofs <<= 1) {
        int v = (t >= ofs) ? soff[t - ofs] : 0;
        __syncthreads();
        soff[t] += v;
        __syncthreads();
    }
    const int total = soff[255];
    const int my0 = soff[t] - cnt;
    for (int k = 0; k < cnt; k++) stage[my0 + k] = tmp[t * ce + lo + k];
    if (t < 128) lcnt[t] = 0;
    __syncthreads();
    for (int i = t; i < total; i += 256) atomicAdd(&lcnt[(stage[i] >> 17) & 127], 1);
    __syncthreads();
    if (t < 128) lofs[t] = lcnt[t];
    __syncthreads();
    for (int ofs = 1; ofs < 128; ofs <<= 1) {
        int v = (t < 128 && t >= ofs) ? lofs[t - ofs] : 0;
        __syncthreads();
        if (t < 128) lofs[t] += v;
        __syncthreads();
    }
    const int base = bucket_base[b];
    if (t < 128) {
        int node = (b << 7) + t;
        int ex = lofs[t] - lcnt[t];
        if (node < N) {
            row_start[node] = base + ex;
            dis[node] = rsqrtf((float)(lcnt[t] + 1));
        }
        lcnt[t] = ex;
    }
    __syncthreads();
    for (int i = t; i < total; i += 256) {
        int v = stage[i];
        int d = (v >> 17) & 127;
        int p = atomicAdd(&lcnt[d], 1);
        col[base + p] = v & 0x1FFFF;
    }
}

// ---------------- helpers ----------------

__device__ __forceinline__ unsigned f_to_bf16(float f) {
    unsigned u = __float_as_uint(f);
    u += 0x7fffu + ((u >> 16) & 1u);   // RNE
    return u >> 16;
}

// ---------------- per-layer compute ----------------

// hw = (X @ W) * dis, bf16 out, via MFMA (16-node x 64-feature tile / wave).
template<bool BF16_IN>
__global__ __launch_bounds__(256) void k_gemm_mfma(
        const void* __restrict__ Xv, const float* __restrict__ W,
        const float* __restrict__ dis, unsigned short* __restrict__ out, int N) {
    const int wave = threadIdx.x >> 6;
    const int lane = threadIdx.x & 63;
    const int lrow = lane & 15;
    const int kgrp = (lane >> 4) * 8;

    short8 bfrag[4][2];
#pragma unroll
    for (int c = 0; c < 4; c++) {
#pragma unroll
        for (int h = 0; h < 2; h++) {
            short8 b;
#pragma unroll
            for (int j = 0; j < 8; j++) {
                float wv = W[(size_t)(h * 32 + kgrp + j) * 64 + c * 16 + lrow];
                b[j] = (short)f_to_bf16(wv);
            }
            bfrag[c][h] = b;
        }
    }

    const int ntiles = N >> 4;   // N = 100000 = 16 * 6250, no tail
    const int nwaves = gridDim.x * 4;
    for (int tile = blockIdx.x * 4 + wave; tile < ntiles; tile += nwaves) {
        const int m = tile * 16 + lrow;
        short8 afrag0, afrag1;
        if (BF16_IN) {
            const unsigned short* Xb = (const unsigned short*)Xv;
            afrag0 = *(const short8*)&Xb[(size_t)m * 64 + kgrp];
            afrag1 = *(const short8*)&Xb[(size_t)m * 64 + 32 + kgrp];
        } else {
            const float* Xf = (const float*)Xv;
            short8 a0, a1;
#pragma unroll
            for (int j = 0; j < 8; j++) {
                a0[j] = (short)f_to_bf16(Xf[(size_t)m * 64 + kgrp + j]);
                a1[j] = (short)f_to_bf16(Xf[(size_t)m * 64 + 32 + kgrp + j]);
            }
            afrag0 = a0; afrag1 = a1;
        }
        f32x4 acc0 = {0.f, 0.f, 0.f, 0.f};
        f32x4 acc1 = {0.f, 0.f, 0.f, 0.f};
        f32x4 acc2 = {0.f, 0.f, 0.f, 0.f};
        f32x4 acc3 = {0.f, 0.f, 0.f, 0.f};
        acc0 = __builtin_amdgcn_mfma_f32_16x16x32_bf16(afrag0, bfrag[0][0], acc0, 0, 0, 0);
        acc1 = __builtin_amdgcn_mfma_f32_16x16x32_bf16(afrag0, bfrag[1][0], acc1, 0, 0, 0);
        acc2 = __builtin_amdgcn_mfma_f32_16x16x32_bf16(afrag0, bfrag[2][0], acc2, 0, 0, 0);
        acc3 = __builtin_amdgcn_mfma_f32_16x16x32_bf16(afrag0, bfrag[3][0], acc3, 0, 0, 0);
        acc0 = __builtin_amdgcn_mfma_f32_16x16x32_bf16(afrag1, bfrag[0][1], acc0, 0, 0, 0);
        acc1 = __builtin_amdgcn_mfma_f32_16x16x32_bf16(afrag1, bfrag[1][1], acc1, 0, 0, 0);
        acc2 = __builtin_amdgcn_mfma_f32_16x16x32_bf16(afrag1, bfrag[2][1], acc2, 0, 0, 0);
        acc3 = __builtin_amdgcn_mfma_f32_16x16x32_bf16(afrag1, bfrag[3][1], acc3, 0, 0, 0);
#pragma unroll
        for (int r = 0; r < 4; r++) {
            int node = tile * 16 + (lane >> 4) * 4 + r;
            float dsc = dis[node];
            unsigned short* o = &out[(size_t)node * 64 + lrow];
            o[0]  = (unsigned short)f_to_bf16(acc0[r] * dsc);
            o[16] = (unsigned short)f_to_bf16(acc1[r] * dsc);
            o[32] = (unsigned short)f_to_bf16(acc2[r] * dsc);
            o[48] = (unsigned short)f_to_bf16(acc3[r] * dsc);
        }
    }
}

// h[n,f] = relu( dis[n]*(hw[n,f] + sum_e hw[col[e],f]) + b[f] ), bf16 in/out.
// 8 edge-slots x 8 feature-lanes, 16B uint4 loads: halves memory-path
// instruction count per edge vs the 4x16 layout (R22 plateau experiment).
// Shfl sites remain wave-uniform; tail is one clamped 8-edge burst.
__global__ __launch_bounds__(256) void k_gather_bf(
        const unsigned short* __restrict__ hw, const int* __restrict__ row_start,
        const int* __restrict__ col, const float* __restrict__ dis,
        const float* __restrict__ bias, unsigned short* __restrict__ out, int N) {
    const int wave = threadIdx.x >> 6;
    const int lane = threadIdx.x & 63;
    const int r = lane >> 3;      // edge slot 0..7
    const int u = lane & 7;       // feature octet 8u..8u+7
    float b8[8];
#pragma unroll
    for (int j = 0; j < 8; j++) b8[j] = bias[8 * u + j];
    const int nwaves = gridDim.x * 4;
    for (int node = blockIdx.x * 4 + wave; node < N; node += nwaves) {
        const int s = row_start[node];
        const int e = row_start[node + 1];
        const float d = dis[node];
        const int deg = e - s;
        int myc = 0;
        if (lane < deg) myc = col[s + lane];
        float a[8];
        if (r == 0) {   // self loop
            uint4 w = *(const uint4*)&hw[(size_t)node * 64 + 8 * u];
            a[0] = __uint_as_float(w.x << 16); a[1] = __uint_as_float(w.x & 0xffff0000u);
            a[2] = __uint_as_float(w.y << 16); a[3] = __uint_as_float(w.y & 0xffff0000u);
            a[4] = __uint_as_float(w.z << 16); a[5] = __uint_as_float(w.z & 0xffff0000u);
            a[6] = __uint_as_float(w.w << 16); a[7] = __uint_as_float(w.w & 0xffff0000u);
        } else {
#pragma unroll
            for (int j = 0; j < 8; j++) a[j] = 0.f;
        }
        const int dm = min(deg, 64);   // wave-uniform
        int kk = 0;
        for (; kk + 16 <= dm; kk += 16) {   // 16 edges via 2 loads (32 lines)
            int c0 = __shfl(myc, kk + r);
            int c1 = __shfl(myc, kk + 8 + r);
            const uint4 w0 = *(const uint4*)&hw[(size_t)c0 * 64 + 8 * u];
            const uint4 w1 = *(const uint4*)&hw[(size_t)c1 * 64 + 8 * u];
            a[0] += __uint_as_float(w0.x << 16); a[1] += __uint_as_float(w0.x & 0xffff0000u);
            a[2] += __uint_as_float(w0.y << 16); a[3] += __uint_as_float(w0.y & 0xffff0000u);
            a[4] += __uint_as_float(w0.z << 16); a[5] += __uint_as_float(w0.z & 0xffff0000u);
            a[6] += __uint_as_float(w0.w << 16); a[7] += __uint_as_float(w0.w & 0xffff0000u);
            a[0] += __uint_as_float(w1.x << 16); a[1] += __uint_as_float(w1.x & 0xffff0000u);
            a[2] += __uint_as_float(w1.y << 16); a[3] += __uint_as_float(w1.y & 0xffff0000u);
            a[4] += __uint_as_float(w1.z << 16); a[5] += __uint_as_float(w1.z & 0xffff0000u);
            a[6] += __uint_as_float(w1.w << 16); a[7] += __uint_as_float(w1.w & 0xffff0000u);
        }
        if (kk + 8 <= dm) {                 // 8 edges via 1 load (16 lines)
            int c0 = __shfl(myc, kk + r);
            const uint4 w0 = *(const uint4*)&hw[(size_t)c0 * 64 + 8 * u];
            a[0] += __uint_as_float(w0.x << 16); a[1] += __uint_as_float(w0.x & 0xffff0000u);
            a[2] += __uint_as_float(w0.y << 16); a[3] += __uint_as_float(w0.y & 0xffff0000u);
            a[4] += __uint_as_float(w0.z << 16); a[5] += __uint_as_float(w0.z & 0xffff0000u);
            a[6] += __uint_as_float(w0.w << 16); a[7] += __uint_as_float(w0.w & 0xffff0000u);
            kk += 8;
        }
        if (kk < dm) {                      // clamped, predicated tail (<8)
            int idx = kk + r;
            int c = __shfl(myc, min(idx, dm - 1));
            const uint4 w0 = *(const uint4*)&hw[(size_t)c * 64 + 8 * u];
            if (idx < dm) {
                a[0] += __uint_as_float(w0.x << 16); a[1] += __uint_as_float(w0.x & 0xffff0000u);
                a[2] += __uint_as_float(w0.y << 16); a[3] += __uint_as_float(w0.y & 0xffff0000u);
                a[4] += __uint_as_float(w0.z << 16); a[5] += __uint_as_float(w0.z & 0xffff0000u);
                a[6] += __uint_as_float(w0.w << 16); a[7] += __uint_as_float(w0.w & 0xffff0000u);
            }
        }
        for (int j = s + 64 + r; j < e; j += 8) {   // rare: degree > 64
            int c = col[j];
            const uint4 w0 = *(const uint4*)&hw[(size_t)c * 64 + 8 * u];
            a[0] += __uint_as_float(w0.x << 16); a[1] += __uint_as_float(w0.x & 0xffff0000u);
            a[2] += __uint_as_float(w0.y << 16); a[3] += __uint_as_float(w0.y & 0xffff0000u);
            a[4] += __uint_as_float(w0.z << 16); a[5] += __uint_as_float(w0.z & 0xffff0000u);
            a[6] += __uint_as_float(w0.w << 16); a[7] += __uint_as_float(w0.w & 0xffff0000u);
        }
        // reduce across the 8 slots (lanes l^8, l^16, l^32)
#pragma unroll
        for (int j = 0; j < 8; j++) a[j] += __shfl_xor(a[j], 8);
#pragma unroll
        for (int j = 0; j < 8; j++) a[j] += __shfl_xor(a[j], 16);
#pragma unroll
        for (int j = 0; j < 8; j++) a[j] += __shfl_xor(a[j], 32);
        if (r == 0) {
            uint4 o;
            float h0 = fmaxf(a[0] * d + b8[0], 0.f);
            float h1 = fmaxf(a[1] * d + b8[1], 0.f);
            float h2 = fmaxf(a[2] * d + b8[2], 0.f);
            float h3 = fmaxf(a[3] * d + b8[3], 0.f);
            float h4 = fmaxf(a[4] * d + b8[4], 0.f);
            float h5 = fmaxf(a[5] * d + b8[5], 0.f);
            float h6 = fmaxf(a[6] * d + b8[6], 0.f);
            float h7 = fmaxf(a[7] * d + b8[7], 0.f);
            o.x = f_to_bf16(h0) | (f_to_bf16(h1) << 16);
            o.y = f_to_bf16(h2) | (f_to_bf16(h3) << 16);
            o.z = f_to_bf16(h4) | (f_to_bf16(h5) << 16);
            o.w = f_to_bf16(h6) | (f_to_bf16(h7) << 16);
            *(uint4*)&out[(size_t)node * 64 + 8 * u] = o;
        }
    }
}

// ---------------- pool + MLP (fused, one block per graph) ----------------

__global__ __launch_bounds__(256) void k_pool_mlp(
        const unsigned short* __restrict__ h, const int* __restrict__ batch,
        int N, const float* __restrict__ Wc1, const float* __restrict__ bc1,
        const float* __restrict__ Wc2, const float* __restrict__ bc2,
        float* __restrict__ out) {
    __shared__ float part[4][64];
    __shared__ float sh[64];
    const int g = blockIdx.x;
    const int w = threadIdx.x >> 6;
    const int lane = threadIdx.x & 63;
    int lo = 0, hi = N;
    while (lo < hi) { int mid = (lo + hi) >> 1; if (batch[mid] < g) lo = mid + 1; else hi = mid; }
    int s = lo;
    lo = 0; hi = N;
    while (lo < hi) { int mid = (lo + hi) >> 1; if (batch[mid] < g + 1) lo = mid + 1; else hi = mid; }
    int e = lo;
    float acc = 0.f;
    for (int i = s + w; i < e; i += 4) {
        unsigned short u = h[(size_t)i * 64 + lane];
        acc += __uint_as_float((unsigned)u << 16);
    }
    part[w][lane] = acc;
    __syncthreads();
    if (threadIdx.x < 64) {
        float v = part[0][threadIdx.x] + part[1][threadIdx.x]
                + part[2][threadIdx.x] + part[3][threadIdx.x];
        sh[threadIdx.x] = v / fmaxf((float)(e - s), 1.f);
    }
    __syncthreads();
    if (w == 0) {
        float p = 0.f;
        if (lane < 32) {
            float z = bc1[lane];
#pragma unroll
            for (int f = 0; f < 64; f++) z += sh[f] * Wc1[f * 32 + lane];
            z = fmaxf(z, 0.f);
            p = z * Wc2[lane];
        }
        for (int ofs = 32; ofs > 0; ofs >>= 1) p += __shfl_down(p, ofs);
        if (lane == 0) out[g] = p + bc2[0];
    }
}

// ---------------- launch ----------------

extern "C" void kernel_launch(void* const* d_in, const int* in_sizes, int n_in,
                              void* d_out, int out_size, void* d_ws, size_t ws_size,
                              hipStream_t stream) {
    const float* x     = (const float*)d_in[0];
    const int*   ei    = (const int*)d_in[1];
    const int*   batch = (const int*)d_in[2];
    const float* W1 = (const float*)d_in[3];  const float* b1 = (const float*)d_in[4];
    const float* W2 = (const float*)d_in[5];  const float* b2 = (const float*)d_in[6];
    const float* W3 = (const float*)d_in[7];  const float* b3 = (const float*)d_in[8];
    const float* Wc1 = (const float*)d_in[9];  const float* bc1 = (const float*)d_in[10];
    const float* Wc2 = (const float*)d_in[11]; const float* bc2 = (const float*)d_in[12];
    float* out = (float*)d_out;

    const int N = in_sizes[0] / 64;   // 100000
    const int E = in_sizes[1] / 2;    // 1600000
    const int G = out_size;           // 1024
    const int* src = ei;
    const int* dst = ei + E;
    const int nb = (N + 127) >> 7;    // 782 buckets
    const int ce = (E + CH - 1) / CH; // 6250 edges/chunk

    char* w = (char*)d_ws;
    auto alloc = [&](size_t bytes) -> void* {
        void* p = (void*)w;
        w += (bytes + 255) & ~(size_t)255;
        return p;
    };
    float* dis         = (float*)alloc((size_t)N * 4);
    int*   row_start   = (int*)alloc((size_t)(N + 1) * 4);
    int*   col         = (int*)alloc((size_t)E * 4);
    int*   counts      = (int*)alloc((size_t)CH * nb * 4);
    int*   loff        = (int*)alloc((size_t)CH * nb * 4);
    int*   bucket_base = (int*)alloc((size_t)(nb + 1) * 4);
    unsigned short* hwbA = (unsigned short*)alloc((size_t)N * 64 * 2);  // bf16 hw
    unsigned short* hb   = (unsigned short*)alloc((size_t)N * 64 * 2);  // bf16 h
    int*   tmp         = (int*)alloc((size_t)E * 4);   // CSR staging
    (void)ws_size; (void)n_in;

    k_cfill<<<CH, 256, 0, stream>>>(src, dst, counts, loff, tmp, E, ce, nb);
    k_bbase<<<1, 1024, 0, stream>>>(counts, bucket_base, row_start, N, E, nb);
    k_pass2<<<nb, 256, 0, stream>>>(tmp, counts, loff, bucket_base, col, row_start, dis, N, ce, nb);

    // layer 1
    k_gemm_mfma<false><<<512, 256, 0, stream>>>(x, W1, dis, hwbA, N);
    k_gather_bf<<<4096, 256, 0, stream>>>(hwbA, row_start, col, dis, b1, hb, N);
    // layer 2
    k_gemm_mfma<true><<<512, 256, 0, stream>>>(hb, W2, dis, hwbA, N);
    k_gather_bf<<<4096, 256, 0, stream>>>(hwbA, row_start, col, dis, b2, hb, N);
    // layer 3
    k_gemm_mfma<true><<<512, 256, 0, stream>>>(hb, W3, dis, hwbA, N);
    k_gather_bf<<<4096, 256, 0, stream>>>(hwbA, row_start, col, dis, b3, hb, N);

    // mean-pool + classifier MLP (fused)
    k_pool_mlp<<<G, 256, 0, stream>>>(hb, batch, N, Wc1, bc1, Wc2, bc2, out);
}

// Round 24
// 207.974 us; speedup vs baseline: 1.0519x; 1.0519x over previous
//
#include <hip/hip_runtime.h>

#define HID 64
#define CH 256       // edge chunks (= k_cfill grid)
#define MAXNB 800    // LDS bucket-counter capacity (>= runtime nb = 782)
#define MAXCE 6400   // LDS chunk-sort capacity (>= runtime ce = 6250)
#define CAP 4096     // LDS bucket-stage capacity (>= max bucket size ~2300)

typedef short short8 __attribute__((ext_vector_type(8)));
typedef float f32x4 __attribute__((ext_vector_type(4)));

// ---------------- CSR build: chunk-local counting sort ----------------

__global__ __launch_bounds__(256) void k_cfill(
        const int* __restrict__ src, const int* __restrict__ dst,
        int* __restrict__ counts, int* __restrict__ loff,
        int* __restrict__ tmp, int E, int ce, int nb) {
    __shared__ int lcnt[MAXNB];
    __shared__ int lscan[MAXNB];
    __shared__ int sums[256];
    __shared__ int sorted[MAXCE];
    const int c = blockIdx.x;
    const int t = threadIdx.x;
    for (int j = t; j < nb; j += 256) lcnt[j] = 0;
    __syncthreads();
    const int s0 = c * ce, e0 = min(s0 + ce, E);
    for (int i = s0 + t; i < e0; i += 256) atomicAdd(&lcnt[dst[i] >> 7], 1);
    __syncthreads();
    for (int j = t; j < nb; j += 256) counts[(size_t)c * nb + j] = lcnt[j];
    const int per = (nb + 255) >> 8;
    const int base = t * per;
    int vals[8];
    int s = 0;
    for (int k = 0; k < per; k++) {
        int f = base + k;
        int v = (f < nb) ? lcnt[f] : 0;
        vals[k] = s;
        s += v;
    }
    sums[t] = s;
    __syncthreads();
    for (int ofs = 1; ofs < 256; ofs <<= 1) {
        int v = (t >= ofs) ? sums[t - ofs] : 0;
        __syncthreads();
        sums[t] += v;
        __syncthreads();
    }
    const int carry = (t > 0) ? sums[t - 1] : 0;
    for (int k = 0; k < per; k++) {
        int f = base + k;
        if (f < nb) {
            int ex = carry + vals[k];
            lscan[f] = ex;
            loff[(size_t)c * nb + f] = ex;
        }
    }
    __syncthreads();
    for (int i = s0 + t; i < e0; i += 256) {
        int d = dst[i];
        int sv = src[i];
        int p = atomicAdd(&lscan[d >> 7], 1);
        sorted[p] = sv | ((d & 127) << 17);
    }
    __syncthreads();
    const int n = e0 - s0;
    for (int j = t; j < n; j += 256) tmp[s0 + j] = sorted[j];
}

// bucket_base = exclusive scan of column sums of counts (no memset/atomics)
__global__ __launch_bounds__(1024) void k_bbase(
        const int* __restrict__ counts, int* __restrict__ bucket_base,
        int* __restrict__ row_start, int N, int E, int nb) {
    __shared__ int sums[1024];
    const int t = threadIdx.x;
    int csum = 0;
    if (t < nb) {
#pragma unroll 8
        for (int c = 0; c < CH; c++) csum += counts[(size_t)c * nb + t];
    }
    sums[t] = csum;
    __syncthreads();
    for (int ofs = 1; ofs < 1024; ofs <<= 1) {
        int u = (t >= ofs) ? sums[t - ofs] : 0;
        __syncthreads();
        sums[t] += u;
        __syncthreads();
    }
    if (t < nb) bucket_base[t] = sums[t] - csum;
    if (t == 0) { bucket_base[nb] = E; row_start[N] = E; }
}

__global__ __launch_bounds__(256) void k_pass2(
        const int* __restrict__ tmp, const int* __restrict__ counts,
        const int* __restrict__ loff, const int* __restrict__ bucket_base,
        int* __restrict__ col, int* __restrict__ row_start,
        float* __restrict__ dis, int N, int ce, int nb) {
    __shared__ int stage[CAP];
    __shared__ int soff[256];
    __shared__ int lcnt[128];
    __shared__ int lofs[128];
    const int b = blockIdx.x;
    const int t = threadIdx.x;
    const int cnt = counts[(size_t)t * nb + b];
    const int lo  = loff[(size_t)t * nb + b];
    soff[t] = cnt;
    __syncthreads();
    for (int ofs = 1; ofs < 256; ofs <<= 1) {
        int v = (t >= ofs) ? soff[t - ofs] : 0;
        __syncthreads();
        soff[t] += v;
        __syncthreads();
    }
    const int total = soff[255];
    const int my0 = soff[t] - cnt;
    for (int k = 0; k < cnt; k++) stage[my0 + k] = tmp[t * ce + lo + k];
    if (t < 128) lcnt[t] = 0;
    __syncthreads();
    for (int i = t; i < total; i += 256) atomicAdd(&lcnt[(stage[i] >> 17) & 127], 1);
    __syncthreads();
    if (t < 128) lofs[t] = lcnt[t];
    __syncthreads();
    for (int ofs = 1; ofs < 128; ofs <<= 1) {
        int v = (t < 128 && t >= ofs) ? lofs[t - ofs] : 0;
        __syncthreads();
        if (t < 128) lofs[t] += v;
        __syncthreads();
    }
    const int base = bucket_base[b];
    if (t < 128) {
        int node = (b << 7) + t;
        int ex = lofs[t] - lcnt[t];
        if (node < N) {
            row_start[node] = base + ex;
            dis[node] = rsqrtf((float)(lcnt[t] + 1));
        }
        lcnt[t] = ex;
    }
    __syncthreads();
    for (int i = t; i < total; i += 256) {
        int v = stage[i];
        int d = (v >> 17) & 127;
        int p = atomicAdd(&lcnt[d], 1);
        col[base + p] = v & 0x1FFFF;
    }
}

// ---------------- helpers ----------------

__device__ __forceinline__ unsigned f_to_bf16(float f) {
    unsigned u = __float_as_uint(f);
    u += 0x7fffu + ((u >> 16) & 1u);   // RNE
    return u >> 16;
}

__device__ __forceinline__ float4 bf4_to_f4(uint2 v) {
    float4 r;
    r.x = __uint_as_float(v.x << 16);
    r.y = __uint_as_float(v.x & 0xffff0000u);
    r.z = __uint_as_float(v.y << 16);
    r.w = __uint_as_float(v.y & 0xffff0000u);
    return r;
}

__device__ __forceinline__ uint2 f4_to_bf4(float4 v) {
    uint2 r;
    r.x = f_to_bf16(v.x) | (f_to_bf16(v.y) << 16);
    r.y = f_to_bf16(v.z) | (f_to_bf16(v.w) << 16);
    return r;
}

// ---------------- per-layer compute ----------------

// hw = (X @ W) * dis, bf16 out, via MFMA (16-node x 64-feature tile / wave).
template<bool BF16_IN>
__global__ __launch_bounds__(256) void k_gemm_mfma(
        const void* __restrict__ Xv, const float* __restrict__ W,
        const float* __restrict__ dis, unsigned short* __restrict__ out, int N) {
    const int wave = threadIdx.x >> 6;
    const int lane = threadIdx.x & 63;
    const int lrow = lane & 15;
    const int kgrp = (lane >> 4) * 8;

    short8 bfrag[4][2];
#pragma unroll
    for (int c = 0; c < 4; c++) {
#pragma unroll
        for (int h = 0; h < 2; h++) {
            short8 b;
#pragma unroll
            for (int j = 0; j < 8; j++) {
                float wv = W[(size_t)(h * 32 + kgrp + j) * 64 + c * 16 + lrow];
                b[j] = (short)f_to_bf16(wv);
            }
            bfrag[c][h] = b;
        }
    }

    const int ntiles = N >> 4;   // N = 100000 = 16 * 6250, no tail
    const int nwaves = gridDim.x * 4;
    for (int tile = blockIdx.x * 4 + wave; tile < ntiles; tile += nwaves) {
        const int m = tile * 16 + lrow;
        short8 afrag0, afrag1;
        if (BF16_IN) {
            const unsigned short* Xb = (const unsigned short*)Xv;
            afrag0 = *(const short8*)&Xb[(size_t)m * 64 + kgrp];
            afrag1 = *(const short8*)&Xb[(size_t)m * 64 + 32 + kgrp];
        } else {
            const float* Xf = (const float*)Xv;
            short8 a0, a1;
#pragma unroll
            for (int j = 0; j < 8; j++) {
                a0[j] = (short)f_to_bf16(Xf[(size_t)m * 64 + kgrp + j]);
                a1[j] = (short)f_to_bf16(Xf[(size_t)m * 64 + 32 + kgrp + j]);
            }
            afrag0 = a0; afrag1 = a1;
        }
        f32x4 acc0 = {0.f, 0.f, 0.f, 0.f};
        f32x4 acc1 = {0.f, 0.f, 0.f, 0.f};
        f32x4 acc2 = {0.f, 0.f, 0.f, 0.f};
        f32x4 acc3 = {0.f, 0.f, 0.f, 0.f};
        acc0 = __builtin_amdgcn_mfma_f32_16x16x32_bf16(afrag0, bfrag[0][0], acc0, 0, 0, 0);
        acc1 = __builtin_amdgcn_mfma_f32_16x16x32_bf16(afrag0, bfrag[1][0], acc1, 0, 0, 0);
        acc2 = __builtin_amdgcn_mfma_f32_16x16x32_bf16(afrag0, bfrag[2][0], acc2, 0, 0, 0);
        acc3 = __builtin_amdgcn_mfma_f32_16x16x32_bf16(afrag0, bfrag[3][0], acc3, 0, 0, 0);
        acc0 = __builtin_amdgcn_mfma_f32_16x16x32_bf16(afrag1, bfrag[0][1], acc0, 0, 0, 0);
        acc1 = __builtin_amdgcn_mfma_f32_16x16x32_bf16(afrag1, bfrag[1][1], acc1, 0, 0, 0);
        acc2 = __builtin_amdgcn_mfma_f32_16x16x32_bf16(afrag1, bfrag[2][1], acc2, 0, 0, 0);
        acc3 = __builtin_amdgcn_mfma_f32_16x16x32_bf16(afrag1, bfrag[3][1], acc3, 0, 0, 0);
#pragma unroll
        for (int r = 0; r < 4; r++) {
            int node = tile * 16 + (lane >> 4) * 4 + r;
            float dsc = dis[node];
            unsigned short* o = &out[(size_t)node * 64 + lrow];
            o[0]  = (unsigned short)f_to_bf16(acc0[r] * dsc);
            o[16] = (unsigned short)f_to_bf16(acc1[r] * dsc);
            o[32] = (unsigned short)f_to_bf16(acc2[r] * dsc);
            o[48] = (unsigned short)f_to_bf16(acc3[r] * dsc);
        }
    }
}

// h[n,f] = relu( dis[n]*(hw[n,f] + sum_e hw[col[e],f]) + b[f] ), bf16 in/out.
// Coalesced col load -> shfl distribution; 16/8/4-edge tiers (R20 best).
__global__ __launch_bounds__(256) void k_gather_bf(
        const unsigned short* __restrict__ hw, const int* __restrict__ row_start,
        const int* __restrict__ col, const float* __restrict__ dis,
        const float* __restrict__ bias, unsigned short* __restrict__ out, int N) {
    const int wave = threadIdx.x >> 6;
    const int lane = threadIdx.x & 63;
    const int q = lane >> 4;
    const int t = lane & 15;
    const float4 b4 = *(const float4*)&bias[4 * t];
    const int nwaves = gridDim.x * 4;
    for (int node = blockIdx.x * 4 + wave; node < N; node += nwaves) {
        const int s = row_start[node];
        const int e = row_start[node + 1];
        const float d = dis[node];
        const int deg = e - s;
        int myc = 0;
        if (lane < deg) myc = col[s + lane];
        float4 acc;
        if (q == 0) {
            acc = bf4_to_f4(*(const uint2*)&hw[(size_t)node * 64 + 4 * t]);  // self loop
        } else {
            acc.x = 0.f; acc.y = 0.f; acc.z = 0.f; acc.w = 0.f;
        }
        const int dm = min(deg, 64);   // wave-uniform
        int kk = 0;
        for (; kk + 16 <= dm; kk += 16) {
            int c0 = __shfl(myc, kk + q);
            int c1 = __shfl(myc, kk + q + 4);
            int c2 = __shfl(myc, kk + q + 8);
            int c3 = __shfl(myc, kk + q + 12);
            const uint2 w0 = *(const uint2*)&hw[(size_t)c0 * 64 + 4 * t];
            const uint2 w1 = *(const uint2*)&hw[(size_t)c1 * 64 + 4 * t];
            const uint2 w2 = *(const uint2*)&hw[(size_t)c2 * 64 + 4 * t];
            const uint2 w3 = *(const uint2*)&hw[(size_t)c3 * 64 + 4 * t];
            float4 v;
            v = bf4_to_f4(w0); acc.x += v.x; acc.y += v.y; acc.z += v.z; acc.w += v.w;
            v = bf4_to_f4(w1); acc.x += v.x; acc.y += v.y; acc.z += v.z; acc.w += v.w;
            v = bf4_to_f4(w2); acc.x += v.x; acc.y += v.y; acc.z += v.z; acc.w += v.w;
            v = bf4_to_f4(w3); acc.x += v.x; acc.y += v.y; acc.z += v.z; acc.w += v.w;
        }
        if (kk + 8 <= dm) {
            int c0 = __shfl(myc, kk + q);
            int c1 = __shfl(myc, kk + q + 4);
            const uint2 w0 = *(const uint2*)&hw[(size_t)c0 * 64 + 4 * t];
            const uint2 w1 = *(const uint2*)&hw[(size_t)c1 * 64 + 4 * t];
            float4 v;
            v = bf4_to_f4(w0); acc.x += v.x; acc.y += v.y; acc.z += v.z; acc.w += v.w;
            v = bf4_to_f4(w1); acc.x += v.x; acc.y += v.y; acc.z += v.z; acc.w += v.w;
            kk += 8;
        }
        for (; kk < dm; kk += 4) {
            int idx = kk + q;
            int c = __shfl(myc, min(idx, dm - 1));
            const uint2 wv = *(const uint2*)&hw[(size_t)c * 64 + 4 * t];
            if (idx < dm) {
                float4 v = bf4_to_f4(wv);
                acc.x += v.x; acc.y += v.y; acc.z += v.z; acc.w += v.w;
            }
        }
        for (int j = s + 64 + q; j < e; j += 4) {   // rare: degree > 64
            int c = col[j];
            float4 v = bf4_to_f4(*(const uint2*)&hw[(size_t)c * 64 + 4 * t]);
            acc.x += v.x; acc.y += v.y; acc.z += v.z; acc.w += v.w;
        }
        acc.x += __shfl_xor(acc.x, 16); acc.y += __shfl_xor(acc.y, 16);
        acc.z += __shfl_xor(acc.z, 16); acc.w += __shfl_xor(acc.w, 16);
        acc.x += __shfl_xor(acc.x, 32); acc.y += __shfl_xor(acc.y, 32);
        acc.z += __shfl_xor(acc.z, 32); acc.w += __shfl_xor(acc.w, 32);
        if (q == 0) {
            float4 r;
            r.x = fmaxf(acc.x * d + b4.x, 0.f);
            r.y = fmaxf(acc.y * d + b4.y, 0.f);
            r.z = fmaxf(acc.z * d + b4.z, 0.f);
            r.w = fmaxf(acc.w * d + b4.w, 0.f);
            *(uint2*)&out[(size_t)node * 64 + 4 * t] = f4_to_bf4(r);
        }
    }
}

// ---------------- pool + MLP (fused, one block per graph) ----------------

__global__ __launch_bounds__(256) void k_pool_mlp(
        const unsigned short* __restrict__ h, const int* __restrict__ batch,
        int N, const float* __restrict__ Wc1, const float* __restrict__ bc1,
        const float* __restrict__ Wc2, const float* __restrict__ bc2,
        float* __restrict__ out) {
    __shared__ float part[4][64];
    __shared__ float sh[64];
    const int g = blockIdx.x;
    const int w = threadIdx.x >> 6;
    const int lane = threadIdx.x & 63;
    int lo = 0, hi = N;
    while (lo < hi) { int mid = (lo + hi) >> 1; if (batch[mid] < g) lo = mid + 1; else hi = mid; }
    int s = lo;
    lo = 0; hi = N;
    while (lo < hi) { int mid = (lo + hi) >> 1; if (batch[mid] < g + 1) lo = mid + 1; else hi = mid; }
    int e = lo;
    float acc = 0.f;
    for (int i = s + w; i < e; i += 4) {
        unsigned short u = h[(size_t)i * 64 + lane];
        acc += __uint_as_float((unsigned)u << 16);
    }
    part[w][lane] = acc;
    __syncthreads();
    if (threadIdx.x < 64) {
        float v = part[0][threadIdx.x] + part[1][threadIdx.x]
                + part[2][threadIdx.x] + part[3][threadIdx.x];
        sh[threadIdx.x] = v / fmaxf((float)(e - s), 1.f);
    }
    __syncthreads();
    if (w == 0) {
        float p = 0.f;
        if (lane < 32) {
            float z = bc1[lane];
#pragma unroll
            for (int f = 0; f < 64; f++) z += sh[f] * Wc1[f * 32 + lane];
            z = fmaxf(z, 0.f);
            p = z * Wc2[lane];
        }
        for (int ofs = 32; ofs > 0; ofs >>= 1) p += __shfl_down(p, ofs);
        if (lane == 0) out[g] = p + bc2[0];
    }
}

// ---------------- launch ----------------

extern "C" void kernel_launch(void* const* d_in, const int* in_sizes, int n_in,
                              void* d_out, int out_size, void* d_ws, size_t ws_size,
                              hipStream_t stream) {
    const float* x     = (const float*)d_in[0];
    const int*   ei    = (const int*)d_in[1];
    const int*   batch = (const int*)d_in[2];
    const float* W1 = (const float*)d_in[3];  const float* b1 = (const float*)d_in[4];
    const float* W2 = (const float*)d_in[5];  const float* b2 = (const float*)d_in[6];
    const float* W3 = (const float*)d_in[7];  const float* b3 = (const float*)d_in[8];
    const float* Wc1 = (const float*)d_in[9];  const float* bc1 = (const float*)d_in[10];
    const float* Wc2 = (const float*)d_in[11]; const float* bc2 = (const float*)d_in[12];
    float* out = (float*)d_out;

    const int N = in_sizes[0] / 64;   // 100000
    const int E = in_sizes[1] / 2;    // 1600000
    const int G = out_size;           // 1024
    const int* src = ei;
    const int* dst = ei + E;
    const int nb = (N + 127) >> 7;    // 782 buckets
    const int ce = (E + CH - 1) / CH; // 6250 edges/chunk

    char* w = (char*)d_ws;
    auto alloc = [&](size_t bytes) -> void* {
        void* p = (void*)w;
        w += (bytes + 255) & ~(size_t)255;
        return p;
    };
    float* dis         = (float*)alloc((size_t)N * 4);
    int*   row_start   = (int*)alloc((size_t)(N + 1) * 4);
    int*   col         = (int*)alloc((size_t)E * 4);
    int*   counts      = (int*)alloc((size_t)CH * nb * 4);
    int*   loff        = (int*)alloc((size_t)CH * nb * 4);
    int*   bucket_base = (int*)alloc((size_t)(nb + 1) * 4);
    unsigned short* hwbA = (unsigned short*)alloc((size_t)N * 64 * 2);  // bf16 hw
    unsigned short* hb   = (unsigned short*)alloc((size_t)N * 64 * 2);  // bf16 h
    int*   tmp         = (int*)alloc((size_t)E * 4);   // CSR staging
    (void)ws_size; (void)n_in;

    k_cfill<<<CH, 256, 0, stream>>>(src, dst, counts, loff, tmp, E, ce, nb);
    k_bbase<<<1, 1024, 0, stream>>>(counts, bucket_base, row_start, N, E, nb);
    k_pass2<<<nb, 256, 0, stream>>>(tmp, counts, loff, bucket_base, col, row_start, dis, N, ce, nb);

    // layer 1
    k_gemm_mfma<false><<<512, 256, 0, stream>>>(x, W1, dis, hwbA, N);
    k_gather_bf<<<4096, 256, 0, stream>>>(hwbA, row_start, col, dis, b1, hb, N);
    // layer 2
    k_gemm_mfma<true><<<512, 256, 0, stream>>>(hb, W2, dis, hwbA, N);
    k_gather_bf<<<4096, 256, 0, stream>>>(hwbA, row_start, col, dis, b2, hb, N);
    // layer 3
    k_gemm_mfma<true><<<512, 256, 0, stream>>>(hb, W3, dis, hwbA, N);
    k_gather_bf<<<4096, 256, 0, stream>>>(hwbA, row_start, col, dis, b3, hb, N);

    // mean-pool + classifier MLP (fused)
    k_pool_mlp<<<G, 256, 0, stream>>>(hb, batch, N, Wc1, bc1, Wc2, bc2, out);
}